// Round 10
// baseline (242.416 us; speedup 1.0000x reference)
//
#include <hip/hip_runtime.h>
#include <hip/hip_bf16.h>
#include <cstdint>
#include <cstddef>

typedef __bf16 bf16_t;
typedef __bf16 bf16x8 __attribute__((ext_vector_type(8)));
typedef __bf16 bf16x4 __attribute__((ext_vector_type(4)));
typedef float f32x4 __attribute__((ext_vector_type(4)));

#define DEVINL static __device__ __forceinline__

constexpr int B_ = 4, S_ = 2048, D_ = 512, H_ = 8, HD_ = 64;
constexpr int M_ = B_ * S_;   // 8192
constexpr int NIN = 14;

DEVINL bf16x8 load8g(const bf16_t* p) { return *reinterpret_cast<const bf16x8*>(p); }

// XOR-swizzle: permute 16B-chunk index by row&7 within each aligned 64-elem group.
// Producers store swizzled; gl2lds stages contiguously; LDS fragment reads use swcol
// -> 2-way banks (free, m136) instead of 16-way on unpadded 128B rows.
DEVINL int swcol(int col, int row) {
  return (col & ~63) | ((((col >> 3) ^ row) & 7) << 3) | (col & 7);
}

// async global->LDS, 16 B/lane. LDS dest is wave-uniform base + lane*16 (m104/m108).
DEVINL void gl2lds(const bf16_t* g, bf16_t* l) {
  __builtin_amdgcn_global_load_lds(
      (const __attribute__((address_space(1))) void*)g,
      (__attribute__((address_space(3))) void*)l, 16, 0, 0);
}

DEVINL void stage16(bf16_t* dst, const void* src, size_t off, bool f32) {
  if (f32) {
    const float* p = (const float*)src + off;
    bf16x8 v0, v1;
#pragma unroll
    for (int j = 0; j < 8; ++j) { v0[j] = (bf16_t)p[j]; v1[j] = (bf16_t)p[8 + j]; }
    *reinterpret_cast<bf16x8*>(dst)     = v0;
    *reinterpret_cast<bf16x8*>(dst + 8) = v1;
  } else {
    const bf16_t* p = (const bf16_t*)src + off;
    *reinterpret_cast<bf16x8*>(dst)     = load8g(p);
    *reinterpret_cast<bf16x8*>(dst + 8) = load8g(p + 8);
  }
}

DEVINL float readf(const void* p, size_t i, bool f32) {
  return f32 ? ((const float*)p)[i] : (float)((const bf16_t*)p)[i];
}

// ---------------- dtype detect: flags[i]=1 iff input i is float32 ----------------
struct DetectArgs { const uint16_t* p[NIN]; int n[NIN]; int* flags; };

__global__ __launch_bounds__(64) void detect_kernel(DetectArgs a) {
  const int z = blockIdx.x;
  const uint16_t* p = a.p[z];
  const int n = a.n[z];
  const int t = threadIdx.x;
  int cnt = 0;
  for (int i = t; i < n; i += 64) {
    const int e = (p[i] >> 7) & 0xFF;
    cnt += (e >= 200);
  }
#pragma unroll
  for (int off = 32; off > 0; off >>= 1) cnt += __shfl_down(cnt, off, 64);
  if (t == 0) a.flags[z] = (cnt > 16) ? 1 : 0;
}

// -------- cvt: mod features -> packed bf16, SWIZZLED layout (gl2lds consumer) --------
struct CvtArgs { const void* src[2]; bf16_t* dst[2]; int idx[2]; const int* flags; };

__global__ __launch_bounds__(256) void cvt_kernel(CvtArgs a) {
  const int z = blockIdx.y;
  const bool f32 = a.flags[a.idx[z]] != 0;
  const size_t i = ((size_t)blockIdx.x * 256 + threadIdx.x) * 8;
  const int row = (int)(i >> 9);
  const int col = (int)(i & 511);
  bf16_t* dst = a.dst[z] + (size_t)row * 512 + swcol(col, row);
  if (f32) {
    const float* p = (const float*)a.src[z] + i;
    bf16x8 v;
#pragma unroll
    for (int j = 0; j < 8; ++j) v[j] = (bf16_t)p[j];
    *reinterpret_cast<bf16x8*>(dst) = v;
  } else {
    *reinterpret_cast<bf16x8*>(dst) = load8g((const bf16_t*)a.src[z] + i);
  }
}

// -------- weight transpose: WT[n][k] = W[k][n], SWIZZLED output (gl2lds consumer) --------
struct TransArgs { const void* src[6]; int srcIdx[6]; bf16_t* dst[6]; const int* flags; };

__global__ __launch_bounds__(256) void transpose_kernel(TransArgs a) {
  __shared__ bf16_t tile[64][80];
  const int w = blockIdx.z;
  const void* src = a.src[w];
  const bool f32 = a.flags[a.srcIdx[w]] != 0;
  bf16_t* dst = a.dst[w];
  const int k0 = blockIdx.x * 64, n0 = blockIdx.y * 64;
  const int t = threadIdx.x;
  const int r = t >> 2, c0 = (t & 3) * 16;
  stage16(&tile[r][c0], src, (size_t)(k0 + r) * 512 + n0 + c0, f32);
  __syncthreads();
  const int orow = n0 + r;
  bf16_t* o = dst + (size_t)orow * 512;
#pragma unroll
  for (int half = 0; half < 2; ++half) {
    bf16x8 ov;
#pragma unroll
    for (int j = 0; j < 8; ++j) ov[j] = tile[c0 + half * 8 + j][r];
    *reinterpret_cast<bf16x8*>(o + swcol(k0 + c0 + half * 8, orow)) = ov;
  }
}

// ---------- plain GEMM + bias, 128x64 tile, BK=128 (4 k-iters: barriers halved) ----------
struct GemmBatch {
  const bf16_t* A[3];
  const bf16_t* Bt[3];
  const void* bias[3]; int bIdx[3];
  void* C[3];          int cIdx[3];
  const int* flags;
};

__global__ __launch_bounds__(256) void gemm_bt_kernel(GemmBatch args) {
  constexpr int K = 512, N = 512;
  __shared__ bf16_t As[128][128];  // 32 KB
  __shared__ bf16_t Bs[64][128];   // 16 KB
  const int z = blockIdx.z;
  const bf16_t* Ag  = args.A[z];
  const bf16_t* Btg = args.Bt[z];
  const void* biag  = args.bias[z];
  void* Cg          = args.C[z];
  const bool bf32 = args.bIdx[z] >= 0 && args.flags[args.bIdx[z]];
  const bool cf32 = args.cIdx[z] >= 0 && args.flags[args.cIdx[z]];
  const int m0 = blockIdx.x * 128, n0 = blockIdx.y * 64;
  const int t = threadIdx.x, lane = t & 63, wave = t >> 6;
  const int l16 = lane & 15, quad = lane >> 4;
  const int wm = wave * 32;
  const int lr = lane >> 4, lc = (lane & 15) * 8;   // staging: 4 rows x 256 B per gl2lds

  f32x4 acc[2][4] = {};

  for (int k0 = 0; k0 < K; k0 += 128) {
    __syncthreads();
#pragma unroll
    for (int s = 0; s < 8; ++s) {
      const int r = wm + s * 4;
      gl2lds(Ag + (size_t)(m0 + r + lr) * K + k0 + lc, &As[r][0]);
    }
#pragma unroll
    for (int s = 0; s < 4; ++s) {
      const int r = wave * 16 + s * 4;
      gl2lds(Btg + (size_t)(n0 + r + lr) * K + k0 + lc, &Bs[r][0]);
    }
    __syncthreads();
#pragma unroll
    for (int ks = 0; ks < 4; ++ks) {
      const int sw = swcol(ks * 32 + quad * 8, l16);
      bf16x8 af[2], bfr[4];
#pragma unroll
      for (int i = 0; i < 2; ++i)
        af[i] = *reinterpret_cast<const bf16x8*>(&As[wm + i * 16 + l16][sw]);
#pragma unroll
      for (int j = 0; j < 4; ++j)
        bfr[j] = *reinterpret_cast<const bf16x8*>(&Bs[j * 16 + l16][sw]);
#pragma unroll
      for (int i = 0; i < 2; ++i)
#pragma unroll
        for (int j = 0; j < 4; ++j)
          acc[i][j] = __builtin_amdgcn_mfma_f32_16x16x32_bf16(af[i], bfr[j], acc[i][j], 0, 0, 0);
    }
  }
  // epilogue: + bias. C/D layout: col=lane&15, row=quad*4+reg (m89). C NORMAL layout.
#pragma unroll
  for (int j = 0; j < 4; ++j) {
    const int col = n0 + j * 16 + l16;
    const float bv = readf(biag, col, bf32);
#pragma unroll
    for (int i = 0; i < 2; ++i) {
      const int rowb = m0 + wm + i * 16 + quad * 4;
#pragma unroll
      for (int r = 0; r < 4; ++r) {
        const size_t idx = (size_t)(rowb + r) * N + col;
        const float v = acc[i][j][r] + bv;
        if (cf32) ((float*)Cg)[idx] = v;
        else      ((bf16_t*)Cg)[idx] = (bf16_t)v;
      }
    }
  }
}

// ------- GEMM + fused modulation, 128x64 tile, BK=128: z=0 -> Kmod (sw); z=1 -> VtT (sw) -------
struct GemmModArgs {
  const bf16_t* A;        // mod2 bf16 (swizzled)
  const bf16_t* Bt[2];    // wtk, wtv (swizzled)
  const void* bias[2]; int bIdx[2];
  const bf16_t* Sc;       // scale [M,512] bf16, normal layout
  const bf16_t* Sh;       // shift [M,512] bf16, normal layout
  bf16_t* Kmod;           // [M,512] swizzled
  bf16_t* VtT;            // [B][H][HD][S] swizzled
  const int* flags;
};

__global__ __launch_bounds__(256) void gemm_mod_kernel(GemmModArgs args) {
  constexpr int K = 512;
  __shared__ bf16_t As[128][128];
  __shared__ bf16_t Bs[64][128];
  const int z = blockIdx.z;
  const bf16_t* Ag  = args.A;
  const bf16_t* Btg = args.Bt[z];
  const void* biag  = args.bias[z];
  const bool bf32 = args.bIdx[z] >= 0 && args.flags[args.bIdx[z]];
  const int m0 = blockIdx.x * 128, n0 = blockIdx.y * 64;
  const int t = threadIdx.x, lane = t & 63, wave = t >> 6;
  const int l16 = lane & 15, quad = lane >> 4;
  const int wm = wave * 32;
  const int lr = lane >> 4, lc = (lane & 15) * 8;

  f32x4 acc[2][4] = {};

  for (int k0 = 0; k0 < K; k0 += 128) {
    __syncthreads();
#pragma unroll
    for (int s = 0; s < 8; ++s) {
      const int r = wm + s * 4;
      gl2lds(Ag + (size_t)(m0 + r + lr) * K + k0 + lc, &As[r][0]);
    }
#pragma unroll
    for (int s = 0; s < 4; ++s) {
      const int r = wave * 16 + s * 4;
      gl2lds(Btg + (size_t)(n0 + r + lr) * K + k0 + lc, &Bs[r][0]);
    }
    __syncthreads();
#pragma unroll
    for (int ks = 0; ks < 4; ++ks) {
      const int sw = swcol(ks * 32 + quad * 8, l16);
      bf16x8 af[2], bfr[4];
#pragma unroll
      for (int i = 0; i < 2; ++i)
        af[i] = *reinterpret_cast<const bf16x8*>(&As[wm + i * 16 + l16][sw]);
#pragma unroll
      for (int j = 0; j < 4; ++j)
        bfr[j] = *reinterpret_cast<const bf16x8*>(&Bs[j * 16 + l16][sw]);
#pragma unroll
      for (int i = 0; i < 2; ++i)
#pragma unroll
        for (int j = 0; j < 4; ++j)
          acc[i][j] = __builtin_amdgcn_mfma_f32_16x16x32_bf16(af[i], bfr[j], acc[i][j], 0, 0, 0);
    }
  }
  // fused epilogue: y = (acc + bias)*scale + shift in fp32, one rounding to bf16
#pragma unroll
  for (int j = 0; j < 4; ++j) {
    const int col = n0 + j * 16 + l16;
    const float bv = readf(biag, col, bf32);
#pragma unroll
    for (int i = 0; i < 2; ++i) {
      const int rowb = m0 + wm + i * 16 + quad * 4;
      if (z == 0) {
#pragma unroll
        for (int r = 0; r < 4; ++r) {
          const int row = rowb + r;
          const size_t idx = (size_t)row * 512 + col;     // sc/sh normal layout
          const float sc = (float)args.Sc[idx], sh = (float)args.Sh[idx];
          args.Kmod[(size_t)row * 512 + swcol(col, row)] = (bf16_t)fmaf(acc[i][j][r] + bv, sc, sh);
        }
      } else {
        bf16x4 pack;
#pragma unroll
        for (int r = 0; r < 4; ++r) {
          const size_t idx = (size_t)(rowb + r) * 512 + col;
          const float sc = (float)args.Sc[idx], sh = (float)args.Sh[idx];
          pack[r] = (bf16_t)fmaf(acc[i][j][r] + bv, sc, sh);
        }
        const int bb = rowb >> 11;      // batch (2048 rows; tile never crosses batch)
        const int ss = rowb & 2047;     // seq (multiple of 4)
        const int hh = col >> 6, dd = col & 63;
        *reinterpret_cast<bf16x4*>(
            args.VtT + (((size_t)(bb * H_ + hh)) * HD_ + dd) * S_ + swcol(ss, dd)) = pack;
      }
    }
  }
}

// ---- flash attention v8: 32-q waves (v6 efficiency), 2-wave blocks -> 6 blocks/CU ----
// S^T = K.Q^T; O^T = V^T.P^T; row sums via ones-MFMA; no running max (scores O(1), clamp 40).
__global__ __launch_bounds__(128) void attn_kernel(const bf16_t* Q, const bf16_t* Kb,
                                                   const bf16_t* Vt, bf16_t* O) {
  __shared__ bf16_t Ks[64][64];       // [key][d]  8 KB unpadded (gl2lds dest)
  __shared__ bf16_t Vs[64][64];       // [d][key]  8 KB
  __shared__ bf16_t Pw[2][32][72];    // per-wave [32 q][64 keys + pad]  9 KB
  const int i = blockIdx.x;
  const int xcd = i & 7, g = i >> 3;
  const int slice = xcd * 4 + (g & 3);   // (b,h): 4 slices per XCD -> 2 MB KV per XCD L2
  const int qt = g >> 2;                 // 0..31
  const int b = slice >> 3, h = slice & 7;
  const int t = threadIdx.x, wave = t >> 6, lane = t & 63;
  const int l16 = lane & 15, quad = lane >> 4;
  const int q0 = qt * 64 + wave * 32;
  const int lr = lane >> 3, lc = (lane & 7) * 8;
  const int sw0 = swcol(quad * 8, l16), sw1 = swcol(32 + quad * 8, l16);

  bf16x8 ones;
#pragma unroll
  for (int j = 0; j < 8; ++j) ones[j] = (bf16_t)1.0f;

  bf16x8 qf[2][2];   // q_buf NORMAL layout
#pragma unroll
  for (int qs = 0; qs < 2; ++qs) {
    const size_t qrow = ((size_t)b * S_ + q0 + qs * 16 + l16) * D_ + h * HD_;
    qf[qs][0] = load8g(Q + qrow + quad * 8);
    qf[qs][1] = load8g(Q + qrow + 32 + quad * 8);
  }

  f32x4 oacc[2][4] = {};
  f32x4 lacc[2] = {};

  const size_t kbase = (size_t)b * S_ * D_ + h * HD_;
  const size_t vbase = ((size_t)(b * H_ + h)) * HD_ * S_;

  for (int kt = 0; kt < S_ / 64; ++kt) {
    const int k0 = kt * 64;
    __syncthreads();
#pragma unroll
    for (int s = 0; s < 4; ++s) {
      const int r = wave * 32 + s * 8;
      gl2lds(Kb + kbase + (size_t)(k0 + r + lr) * D_ + lc, &Ks[r][0]);
      gl2lds(Vt + vbase + (size_t)(r + lr) * S_ + k0 + lc, &Vs[r][0]);
    }
    __syncthreads();
    // ---- S^T[64 keys][32 q] = K . Q^T ----
    f32x4 sacc[4][2] = {};
#pragma unroll
    for (int c = 0; c < 2; ++c) {
      const int sw = c ? sw1 : sw0;
      bf16x8 kf[4];
#pragma unroll
      for (int j = 0; j < 4; ++j)
        kf[j] = *reinterpret_cast<const bf16x8*>(&Ks[j * 16 + l16][sw]);
#pragma unroll
      for (int j = 0; j < 4; ++j)
#pragma unroll
        for (int qs = 0; qs < 2; ++qs)
          sacc[j][qs] = __builtin_amdgcn_mfma_f32_16x16x32_bf16(kf[j], qf[qs][c], sacc[j][qs], 0, 0, 0);
    }
    // ---- P = exp(s/8): lane holds 4 consecutive keys -> packed b64 writes ----
#pragma unroll
    for (int j = 0; j < 4; ++j)
#pragma unroll
      for (int qs = 0; qs < 2; ++qs) {
        bf16x4 pack;
#pragma unroll
        for (int r = 0; r < 4; ++r)
          pack[r] = (bf16_t)__expf(fminf(sacc[j][qs][r] * 0.125f, 40.0f));
        *reinterpret_cast<bf16x4*>(&Pw[wave][qs * 16 + l16][j * 16 + quad * 4]) = pack;
      }
    // ---- O^T += V^T . P^T ; l += ones . P^T (same-wave ds ordering, no barrier) ----
#pragma unroll
    for (int c = 0; c < 2; ++c) {
      const int sw = c ? sw1 : sw0;
      bf16x8 bp[2];
#pragma unroll
      for (int qs = 0; qs < 2; ++qs)
        bp[qs] = *reinterpret_cast<const bf16x8*>(&Pw[wave][qs * 16 + l16][c * 32 + quad * 8]);
      bf16x8 vf[4];
#pragma unroll
      for (int dj = 0; dj < 4; ++dj)
        vf[dj] = *reinterpret_cast<const bf16x8*>(&Vs[dj * 16 + l16][sw]);
#pragma unroll
      for (int qs = 0; qs < 2; ++qs) {
#pragma unroll
        for (int dj = 0; dj < 4; ++dj)
          oacc[qs][dj] = __builtin_amdgcn_mfma_f32_16x16x32_bf16(vf[dj], bp[qs], oacc[qs][dj], 0, 0, 0);
        lacc[qs] = __builtin_amdgcn_mfma_f32_16x16x32_bf16(ones, bp[qs], lacc[qs], 0, 0, 0);
      }
    }
  }
  // ---- epilogue: O[q][d] = O^T[d][q] / l[q]; packed 8B stores, SWIZZLED (feeds g2) ----
#pragma unroll
  for (int qs = 0; qs < 2; ++qs) {
    const float linv = 1.0f / fmaxf(lacc[qs][0], 1e-30f);
    const int q = q0 + qs * 16 + l16;
    const size_t orow = ((size_t)b * S_ + q) * D_ + h * HD_;
#pragma unroll
    for (int dj = 0; dj < 4; ++dj) {
      bf16x4 pack;
#pragma unroll
      for (int r = 0; r < 4; ++r) pack[r] = (bf16_t)(oacc[qs][dj][r] * linv);
      *reinterpret_cast<bf16x4*>(&O[orow + swcol(dj * 16 + quad * 4, q)]) = pack;
    }
  }
}

// ---------------- host launcher ----------------
extern "C" void kernel_launch(void* const* d_in, const int* in_sizes, int n_in,
                              void* d_out, int out_size, void* d_ws, size_t ws_size,
                              hipStream_t stream) {
  (void)n_in; (void)out_size; (void)ws_size;

  char* ws = (char*)d_ws;
  auto alloc = [&](size_t bytes) -> char* {
    char* p = ws; ws += (bytes + 255) & ~(size_t)255; return p;
  };
  int* flags = (int*)alloc(64 * sizeof(int));
  const size_t wbytes = (size_t)512 * 512 * sizeof(bf16_t);
  const size_t fbytes = (size_t)M_ * D_ * sizeof(bf16_t);
  bf16_t* wt    = (bf16_t*)alloc(6 * wbytes);  // 3 MB (swizzled)
  bf16_t* m1b   = (bf16_t*)alloc(fbytes);      // 8 MB mod1 bf16 swizzled; vtb alias after g1a
  bf16_t* m2b   = (bf16_t*)alloc(fbytes);      // 8 MB mod2 bf16 swizzled
  bf16_t* q_buf = (bf16_t*)alloc(fbytes);      // 8 MB normal
  bf16_t* stmp  = (bf16_t*)alloc(fbytes);      // 8 MB normal; attn_b alias after g1b
  bf16_t* shtmp = (bf16_t*)alloc(fbytes);      // 8 MB normal
  bf16_t* kmod  = (bf16_t*)alloc(fbytes);      // 8 MB swizzled
  bf16_t* vtb    = m1b;    // alias: m1b dead after g1a
  bf16_t* attn_b = stmp;   // alias: stmp dead after g1b epilogue

  bf16_t* wtq  = wt + 0 * 512 * 512;
  bf16_t* wtk  = wt + 1 * 512 * 512;
  bf16_t* wtv  = wt + 2 * 512 * 512;
  bf16_t* wts  = wt + 3 * 512 * 512;
  bf16_t* wtsh = wt + 4 * 512 * 512;
  bf16_t* wto  = wt + 5 * 512 * 512;

  DetectArgs da;
  for (int i = 0; i < NIN; ++i) {
    da.p[i] = (const uint16_t*)d_in[i];
    da.n[i] = in_sizes[i] < 2048 ? in_sizes[i] : 2048;
  }
  da.flags = flags;
  hipLaunchKernelGGL(detect_kernel, dim3(NIN), dim3(64), 0, stream, da);

  CvtArgs ca;
  ca.src[0] = d_in[0]; ca.dst[0] = m1b; ca.idx[0] = 0;
  ca.src[1] = d_in[1]; ca.dst[1] = m2b; ca.idx[1] = 1;
  ca.flags = flags;
  hipLaunchKernelGGL(cvt_kernel, dim3(M_ * D_ / 2048, 2), dim3(256), 0, stream, ca);

  TransArgs ta;
  const int widx[6] = {2, 4, 6, 10, 12, 8};
  bf16_t* wdst[6] = {wtq, wtk, wtv, wts, wtsh, wto};
  for (int i = 0; i < 6; ++i) { ta.src[i] = d_in[widx[i]]; ta.srcIdx[i] = widx[i]; ta.dst[i] = wdst[i]; }
  ta.flags = flags;
  hipLaunchKernelGGL(transpose_kernel, dim3(8, 8, 6), dim3(256), 0, stream, ta);

  // g1a: Q, scale, shift projections — 1536 blocks
  GemmBatch g1;
  g1.A[0] = m1b; g1.A[1] = m2b; g1.A[2] = m2b;
  g1.Bt[0] = wtq; g1.Bt[1] = wts; g1.Bt[2] = wtsh;
  g1.bias[0] = d_in[3];  g1.bIdx[0] = 3;
  g1.bias[1] = d_in[11]; g1.bIdx[1] = 11;
  g1.bias[2] = d_in[13]; g1.bIdx[2] = 13;
  g1.C[0] = q_buf; g1.cIdx[0] = -1;
  g1.C[1] = stmp;  g1.cIdx[1] = -1;
  g1.C[2] = shtmp; g1.cIdx[2] = -1;
  g1.flags = flags;
  hipLaunchKernelGGL(gemm_bt_kernel, dim3(M_ / 128, 8, 3), dim3(256), 0, stream, g1);

  // g1b: K, V projections + fused modulation — 1024 blocks
  GemmModArgs gm;
  gm.A = m2b;
  gm.Bt[0] = wtk; gm.Bt[1] = wtv;
  gm.bias[0] = d_in[5]; gm.bIdx[0] = 5;
  gm.bias[1] = d_in[7]; gm.bIdx[1] = 7;
  gm.Sc = stmp; gm.Sh = shtmp;
  gm.Kmod = kmod; gm.VtT = vtb;
  gm.flags = flags;
  hipLaunchKernelGGL(gemm_mod_kernel, dim3(M_ / 128, 8, 2), dim3(256), 0, stream, gm);

  // attn: 1024 blocks x 128 threads = 6 blocks/CU, 32-q waves
  hipLaunchKernelGGL(attn_kernel, dim3(1024), dim3(128), 0, stream,
                     q_buf, kmod, vtb, attn_b);

  // g2: out = attn @ Wo^T + bo — 512 blocks
  GemmBatch g2;
  for (int i = 0; i < 3; ++i) {
    g2.A[i] = attn_b;
    g2.Bt[i] = wto;
    g2.bias[i] = d_in[9]; g2.bIdx[i] = 9;
    g2.C[i] = d_out; g2.cIdx[i] = 0;
  }
  g2.flags = flags;
  hipLaunchKernelGGL(gemm_bt_kernel, dim3(M_ / 128, 8, 1), dim3(256), 0, stream, g2);
}

// Round 11
// 233.402 us; speedup vs baseline: 1.0386x; 1.0386x over previous
//
#include <hip/hip_runtime.h>
#include <hip/hip_bf16.h>
#include <cstdint>
#include <cstddef>

typedef __bf16 bf16_t;
typedef __bf16 bf16x8 __attribute__((ext_vector_type(8)));
typedef __bf16 bf16x4 __attribute__((ext_vector_type(4)));
typedef float f32x4 __attribute__((ext_vector_type(4)));

#define DEVINL static __device__ __forceinline__

constexpr int B_ = 4, S_ = 2048, D_ = 512, H_ = 8, HD_ = 64;
constexpr int M_ = B_ * S_;   // 8192
constexpr int NIN = 14;

DEVINL bf16x8 load8g(const bf16_t* p) { return *reinterpret_cast<const bf16x8*>(p); }

// XOR-swizzle: permute 16B-chunk index by row&7 within each aligned 64-elem group.
// Producers store swizzled; gl2lds stages contiguously; LDS fragment reads use swcol
// -> 2-way banks (free, m136) instead of 16-way on unpadded 128B rows.
DEVINL int swcol(int col, int row) {
  return (col & ~63) | ((((col >> 3) ^ row) & 7) << 3) | (col & 7);
}

// async global->LDS, 16 B/lane. LDS dest is wave-uniform base + lane*16 (m104/m108).
DEVINL void gl2lds(const bf16_t* g, bf16_t* l) {
  __builtin_amdgcn_global_load_lds(
      (const __attribute__((address_space(1))) void*)g,
      (__attribute__((address_space(3))) void*)l, 16, 0, 0);
}

DEVINL void stage16(bf16_t* dst, const void* src, size_t off, bool f32) {
  if (f32) {
    const float* p = (const float*)src + off;
    bf16x8 v0, v1;
#pragma unroll
    for (int j = 0; j < 8; ++j) { v0[j] = (bf16_t)p[j]; v1[j] = (bf16_t)p[8 + j]; }
    *reinterpret_cast<bf16x8*>(dst)     = v0;
    *reinterpret_cast<bf16x8*>(dst + 8) = v1;
  } else {
    const bf16_t* p = (const bf16_t*)src + off;
    *reinterpret_cast<bf16x8*>(dst)     = load8g(p);
    *reinterpret_cast<bf16x8*>(dst + 8) = load8g(p + 8);
  }
}

DEVINL float readf(const void* p, size_t i, bool f32) {
  return f32 ? ((const float*)p)[i] : (float)((const bf16_t*)p)[i];
}

// ---------------- dtype detect: flags[i]=1 iff input i is float32 ----------------
struct DetectArgs { const uint16_t* p[NIN]; int n[NIN]; int* flags; };

__global__ __launch_bounds__(64) void detect_kernel(DetectArgs a) {
  const int z = blockIdx.x;
  const uint16_t* p = a.p[z];
  const int n = a.n[z];
  const int t = threadIdx.x;
  int cnt = 0;
  for (int i = t; i < n; i += 64) {
    const int e = (p[i] >> 7) & 0xFF;
    cnt += (e >= 200);
  }
#pragma unroll
  for (int off = 32; off > 0; off >>= 1) cnt += __shfl_down(cnt, off, 64);
  if (t == 0) a.flags[z] = (cnt > 16) ? 1 : 0;
}

// -------- cvt: mod features -> packed bf16, SWIZZLED layout (gl2lds consumer) --------
struct CvtArgs { const void* src[2]; bf16_t* dst[2]; int idx[2]; const int* flags; };

__global__ __launch_bounds__(256) void cvt_kernel(CvtArgs a) {
  const int z = blockIdx.y;
  const bool f32 = a.flags[a.idx[z]] != 0;
  const size_t i = ((size_t)blockIdx.x * 256 + threadIdx.x) * 8;
  const int row = (int)(i >> 9);
  const int col = (int)(i & 511);
  bf16_t* dst = a.dst[z] + (size_t)row * 512 + swcol(col, row);
  if (f32) {
    const float* p = (const float*)a.src[z] + i;
    bf16x8 v;
#pragma unroll
    for (int j = 0; j < 8; ++j) v[j] = (bf16_t)p[j];
    *reinterpret_cast<bf16x8*>(dst) = v;
  } else {
    *reinterpret_cast<bf16x8*>(dst) = load8g((const bf16_t*)a.src[z] + i);
  }
}

// -------- weight transpose: WT[n][k] = W[k][n], SWIZZLED output (gl2lds consumer) --------
struct TransArgs { const void* src[6]; int srcIdx[6]; bf16_t* dst[6]; const int* flags; };

__global__ __launch_bounds__(256) void transpose_kernel(TransArgs a) {
  __shared__ bf16_t tile[64][80];
  const int w = blockIdx.z;
  const void* src = a.src[w];
  const bool f32 = a.flags[a.srcIdx[w]] != 0;
  bf16_t* dst = a.dst[w];
  const int k0 = blockIdx.x * 64, n0 = blockIdx.y * 64;
  const int t = threadIdx.x;
  const int r = t >> 2, c0 = (t & 3) * 16;
  stage16(&tile[r][c0], src, (size_t)(k0 + r) * 512 + n0 + c0, f32);
  __syncthreads();
  const int orow = n0 + r;
  bf16_t* o = dst + (size_t)orow * 512;
#pragma unroll
  for (int half = 0; half < 2; ++half) {
    bf16x8 ov;
#pragma unroll
    for (int j = 0; j < 8; ++j) ov[j] = tile[c0 + half * 8 + j][r];
    *reinterpret_cast<bf16x8*>(o + swcol(k0 + c0 + half * 8, orow)) = ov;
  }
}

// ---- plain GEMM + bias, 128x64 tile, BK=64, DOUBLE-BUFFERED staging (1 barrier/iter) ----
struct GemmBatch {
  const bf16_t* A[3];
  const bf16_t* Bt[3];
  const void* bias[3]; int bIdx[3];
  void* C[3];          int cIdx[3];
  const int* flags;
};

__global__ __launch_bounds__(256) void gemm_bt_kernel(GemmBatch args) {
  constexpr int K = 512, N = 512;
  __shared__ bf16_t As[2][128][64];   // 32 KB
  __shared__ bf16_t Bs[2][64][64];    // 16 KB
  const int z = blockIdx.z;
  const bf16_t* Ag  = args.A[z];
  const bf16_t* Btg = args.Bt[z];
  const void* biag  = args.bias[z];
  void* Cg          = args.C[z];
  const bool bf32 = args.bIdx[z] >= 0 && args.flags[args.bIdx[z]];
  const bool cf32 = args.cIdx[z] >= 0 && args.flags[args.cIdx[z]];
  const int m0 = blockIdx.x * 128, n0 = blockIdx.y * 64;
  const int t = threadIdx.x, lane = t & 63, wave = t >> 6;
  const int l16 = lane & 15, quad = lane >> 4;
  const int wm = wave * 32;
  const int lr = lane >> 3, lc = (lane & 7) * 8;   // 8 rows x 128 B per gl2lds

  auto stage = [&](int buf, int k0) {
#pragma unroll
    for (int s = 0; s < 4; ++s) {
      const int r = wm + s * 8;
      gl2lds(Ag + (size_t)(m0 + r + lr) * K + k0 + lc, &As[buf][r][0]);
    }
#pragma unroll
    for (int s = 0; s < 2; ++s) {
      const int r = wave * 16 + s * 8;
      gl2lds(Btg + (size_t)(n0 + r + lr) * K + k0 + lc, &Bs[buf][r][0]);
    }
  };

  f32x4 acc[2][4] = {};
  stage(0, 0);

  for (int kt = 0; kt < K / 64; ++kt) {
    const int cur = kt & 1;
    __syncthreads();                    // drains stage(cur) issued one iter ago
    if (kt + 1 < K / 64) stage(1 - cur, (kt + 1) * 64);   // prefetch next
#pragma unroll
    for (int ks = 0; ks < 2; ++ks) {
      const int sw = swcol(ks * 32 + quad * 8, l16);
      bf16x8 af[2], bfr[4];
#pragma unroll
      for (int i = 0; i < 2; ++i)
        af[i] = *reinterpret_cast<const bf16x8*>(&As[cur][wm + i * 16 + l16][sw]);
#pragma unroll
      for (int j = 0; j < 4; ++j)
        bfr[j] = *reinterpret_cast<const bf16x8*>(&Bs[cur][j * 16 + l16][sw]);
#pragma unroll
      for (int i = 0; i < 2; ++i)
#pragma unroll
        for (int j = 0; j < 4; ++j)
          acc[i][j] = __builtin_amdgcn_mfma_f32_16x16x32_bf16(af[i], bfr[j], acc[i][j], 0, 0, 0);
    }
  }
  // epilogue: + bias. C/D layout: col=lane&15, row=quad*4+reg (m89). C NORMAL layout.
#pragma unroll
  for (int j = 0; j < 4; ++j) {
    const int col = n0 + j * 16 + l16;
    const float bv = readf(biag, col, bf32);
#pragma unroll
    for (int i = 0; i < 2; ++i) {
      const int rowb = m0 + wm + i * 16 + quad * 4;
#pragma unroll
      for (int r = 0; r < 4; ++r) {
        const size_t idx = (size_t)(rowb + r) * N + col;
        const float v = acc[i][j][r] + bv;
        if (cf32) ((float*)Cg)[idx] = v;
        else      ((bf16_t*)Cg)[idx] = (bf16_t)v;
      }
    }
  }
}

// ---- GEMM + fused modulation, 128x64, BK=64, dbuf: z=0 -> Kmod (sw); z=1 -> VtT (sw) ----
struct GemmModArgs {
  const bf16_t* A;        // mod2 bf16 (swizzled)
  const bf16_t* Bt[2];    // wtk, wtv (swizzled)
  const void* bias[2]; int bIdx[2];
  const bf16_t* Sc;       // scale [M,512] bf16, normal layout
  const bf16_t* Sh;       // shift [M,512] bf16, normal layout
  bf16_t* Kmod;           // [M,512] swizzled
  bf16_t* VtT;            // [B][H][HD][S] swizzled
  const int* flags;
};

__global__ __launch_bounds__(256) void gemm_mod_kernel(GemmModArgs args) {
  constexpr int K = 512;
  __shared__ bf16_t As[2][128][64];
  __shared__ bf16_t Bs[2][64][64];
  const int z = blockIdx.z;
  const bf16_t* Ag  = args.A;
  const bf16_t* Btg = args.Bt[z];
  const void* biag  = args.bias[z];
  const bool bf32 = args.bIdx[z] >= 0 && args.flags[args.bIdx[z]];
  const int m0 = blockIdx.x * 128, n0 = blockIdx.y * 64;
  const int t = threadIdx.x, lane = t & 63, wave = t >> 6;
  const int l16 = lane & 15, quad = lane >> 4;
  const int wm = wave * 32;
  const int lr = lane >> 3, lc = (lane & 7) * 8;

  auto stage = [&](int buf, int k0) {
#pragma unroll
    for (int s = 0; s < 4; ++s) {
      const int r = wm + s * 8;
      gl2lds(Ag + (size_t)(m0 + r + lr) * K + k0 + lc, &As[buf][r][0]);
    }
#pragma unroll
    for (int s = 0; s < 2; ++s) {
      const int r = wave * 16 + s * 8;
      gl2lds(Btg + (size_t)(n0 + r + lr) * K + k0 + lc, &Bs[buf][r][0]);
    }
  };

  f32x4 acc[2][4] = {};
  stage(0, 0);

  for (int kt = 0; kt < K / 64; ++kt) {
    const int cur = kt & 1;
    __syncthreads();
    if (kt + 1 < K / 64) stage(1 - cur, (kt + 1) * 64);
#pragma unroll
    for (int ks = 0; ks < 2; ++ks) {
      const int sw = swcol(ks * 32 + quad * 8, l16);
      bf16x8 af[2], bfr[4];
#pragma unroll
      for (int i = 0; i < 2; ++i)
        af[i] = *reinterpret_cast<const bf16x8*>(&As[cur][wm + i * 16 + l16][sw]);
#pragma unroll
      for (int j = 0; j < 4; ++j)
        bfr[j] = *reinterpret_cast<const bf16x8*>(&Bs[cur][j * 16 + l16][sw]);
#pragma unroll
      for (int i = 0; i < 2; ++i)
#pragma unroll
        for (int j = 0; j < 4; ++j)
          acc[i][j] = __builtin_amdgcn_mfma_f32_16x16x32_bf16(af[i], bfr[j], acc[i][j], 0, 0, 0);
    }
  }
  // fused epilogue: y = (acc + bias)*scale + shift in fp32, one rounding to bf16
#pragma unroll
  for (int j = 0; j < 4; ++j) {
    const int col = n0 + j * 16 + l16;
    const float bv = readf(biag, col, bf32);
#pragma unroll
    for (int i = 0; i < 2; ++i) {
      const int rowb = m0 + wm + i * 16 + quad * 4;
      if (z == 0) {
#pragma unroll
        for (int r = 0; r < 4; ++r) {
          const int row = rowb + r;
          const size_t idx = (size_t)row * 512 + col;     // sc/sh normal layout
          const float sc = (float)args.Sc[idx], sh = (float)args.Sh[idx];
          args.Kmod[(size_t)row * 512 + swcol(col, row)] = (bf16_t)fmaf(acc[i][j][r] + bv, sc, sh);
        }
      } else {
        bf16x4 pack;
#pragma unroll
        for (int r = 0; r < 4; ++r) {
          const size_t idx = (size_t)(rowb + r) * 512 + col;
          const float sc = (float)args.Sc[idx], sh = (float)args.Sh[idx];
          pack[r] = (bf16_t)fmaf(acc[i][j][r] + bv, sc, sh);
        }
        const int bb = rowb >> 11;      // batch (2048 rows; tile never crosses batch)
        const int ss = rowb & 2047;     // seq (multiple of 4)
        const int hh = col >> 6, dd = col & 63;
        *reinterpret_cast<bf16x4*>(
            args.VtT + (((size_t)(bb * H_ + hh)) * HD_ + dd) * S_ + swcol(ss, dd)) = pack;
      }
    }
  }
}

// ---- flash attention v9: v6 geometry (512 blk x 256 thr, 32-q waves) + dbuf K/V staging ----
// S^T = K.Q^T; O^T = V^T.P^T; row sums via ones-MFMA; no running max (scores O(1), clamp 40).
__global__ __launch_bounds__(256) void attn_kernel(const bf16_t* Q, const bf16_t* Kb,
                                                   const bf16_t* Vt, bf16_t* O) {
  __shared__ bf16_t Ks[2][64][64];    // 16 KB (gl2lds dest, unpadded)
  __shared__ bf16_t Vs[2][64][64];    // 16 KB
  __shared__ bf16_t Pw[4][32][72];    // per-wave [32 q][64 keys + pad] 18 KB
  const int i = blockIdx.x;
  const int xcd = i & 7, g = i >> 3;
  const int slice = xcd * 4 + (g & 3);   // (b,h): 4 slices per XCD -> 2 MB KV per XCD L2
  const int qt = g >> 2;                 // 0..15
  const int b = slice >> 3, h = slice & 7;
  const int t = threadIdx.x, wave = t >> 6, lane = t & 63;
  const int l16 = lane & 15, quad = lane >> 4;
  const int q0 = qt * 128 + wave * 32;
  const int lr = lane >> 3, lc = (lane & 7) * 8;
  const int sw0 = swcol(quad * 8, l16), sw1 = swcol(32 + quad * 8, l16);

  bf16x8 ones;
#pragma unroll
  for (int j = 0; j < 8; ++j) ones[j] = (bf16_t)1.0f;

  bf16x8 qf[2][2];   // q_buf NORMAL layout
#pragma unroll
  for (int qs = 0; qs < 2; ++qs) {
    const size_t qrow = ((size_t)b * S_ + q0 + qs * 16 + l16) * D_ + h * HD_;
    qf[qs][0] = load8g(Q + qrow + quad * 8);
    qf[qs][1] = load8g(Q + qrow + 32 + quad * 8);
  }

  f32x4 oacc[2][4] = {};
  f32x4 lacc[2] = {};

  const size_t kbase = (size_t)b * S_ * D_ + h * HD_;
  const size_t vbase = ((size_t)(b * H_ + h)) * HD_ * S_;

  auto stage = [&](int buf, int k0) {
#pragma unroll
    for (int s = 0; s < 2; ++s) {
      const int r = wave * 16 + s * 8;
      gl2lds(Kb + kbase + (size_t)(k0 + r + lr) * D_ + lc, &Ks[buf][r][0]);
      gl2lds(Vt + vbase + (size_t)(r + lr) * S_ + k0 + lc, &Vs[buf][r][0]);
    }
  };

  stage(0, 0);

  for (int kt = 0; kt < S_ / 64; ++kt) {
    const int cur = kt & 1;
    __syncthreads();                         // drains stage(cur) issued one iter ago
    if (kt + 1 < S_ / 64) stage(1 - cur, (kt + 1) * 64);
    // ---- S^T[64 keys][32 q] = K . Q^T ----
    f32x4 sacc[4][2] = {};
#pragma unroll
    for (int c = 0; c < 2; ++c) {
      const int sw = c ? sw1 : sw0;
      bf16x8 kf[4];
#pragma unroll
      for (int j = 0; j < 4; ++j)
        kf[j] = *reinterpret_cast<const bf16x8*>(&Ks[cur][j * 16 + l16][sw]);
#pragma unroll
      for (int j = 0; j < 4; ++j)
#pragma unroll
        for (int qs = 0; qs < 2; ++qs)
          sacc[j][qs] = __builtin_amdgcn_mfma_f32_16x16x32_bf16(kf[j], qf[qs][c], sacc[j][qs], 0, 0, 0);
    }
    // ---- P = exp(s/8): lane holds 4 consecutive keys -> packed b64 writes ----
#pragma unroll
    for (int j = 0; j < 4; ++j)
#pragma unroll
      for (int qs = 0; qs < 2; ++qs) {
        bf16x4 pack;
#pragma unroll
        for (int r = 0; r < 4; ++r)
          pack[r] = (bf16_t)__expf(fminf(sacc[j][qs][r] * 0.125f, 40.0f));
        *reinterpret_cast<bf16x4*>(&Pw[wave][qs * 16 + l16][j * 16 + quad * 4]) = pack;
      }
    // ---- O^T += V^T . P^T ; l += ones . P^T (same-wave ds ordering, no barrier) ----
#pragma unroll
    for (int c = 0; c < 2; ++c) {
      const int sw = c ? sw1 : sw0;
      bf16x8 bp[2];
#pragma unroll
      for (int qs = 0; qs < 2; ++qs)
        bp[qs] = *reinterpret_cast<const bf16x8*>(&Pw[wave][qs * 16 + l16][c * 32 + quad * 8]);
      bf16x8 vf[4];
#pragma unroll
      for (int dj = 0; dj < 4; ++dj)
        vf[dj] = *reinterpret_cast<const bf16x8*>(&Vs[cur][dj * 16 + l16][sw]);
#pragma unroll
      for (int qs = 0; qs < 2; ++qs) {
#pragma unroll
        for (int dj = 0; dj < 4; ++dj)
          oacc[qs][dj] = __builtin_amdgcn_mfma_f32_16x16x32_bf16(vf[dj], bp[qs], oacc[qs][dj], 0, 0, 0);
        lacc[qs] = __builtin_amdgcn_mfma_f32_16x16x32_bf16(ones, bp[qs], lacc[qs], 0, 0, 0);
      }
    }
  }
  // ---- epilogue: O[q][d] = O^T[d][q] / l[q]; packed 8B stores, SWIZZLED (feeds g2) ----
#pragma unroll
  for (int qs = 0; qs < 2; ++qs) {
    const float linv = 1.0f / fmaxf(lacc[qs][0], 1e-30f);
    const int q = q0 + qs * 16 + l16;
    const size_t orow = ((size_t)b * S_ + q) * D_ + h * HD_;
#pragma unroll
    for (int dj = 0; dj < 4; ++dj) {
      bf16x4 pack;
#pragma unroll
      for (int r = 0; r < 4; ++r) pack[r] = (bf16_t)(oacc[qs][dj][r] * linv);
      *reinterpret_cast<bf16x4*>(&O[orow + swcol(dj * 16 + quad * 4, q)]) = pack;
    }
  }
}

// ---------------- host launcher ----------------
extern "C" void kernel_launch(void* const* d_in, const int* in_sizes, int n_in,
                              void* d_out, int out_size, void* d_ws, size_t ws_size,
                              hipStream_t stream) {
  (void)n_in; (void)out_size; (void)ws_size;

  char* ws = (char*)d_ws;
  auto alloc = [&](size_t bytes) -> char* {
    char* p = ws; ws += (bytes + 255) & ~(size_t)255; return p;
  };
  int* flags = (int*)alloc(64 * sizeof(int));
  const size_t wbytes = (size_t)512 * 512 * sizeof(bf16_t);
  const size_t fbytes = (size_t)M_ * D_ * sizeof(bf16_t);
  bf16_t* wt    = (bf16_t*)alloc(6 * wbytes);  // 3 MB (swizzled)
  bf16_t* m1b   = (bf16_t*)alloc(fbytes);      // 8 MB mod1 bf16 swizzled; vtb alias after g1a
  bf16_t* m2b   = (bf16_t*)alloc(fbytes);      // 8 MB mod2 bf16 swizzled
  bf16_t* q_buf = (bf16_t*)alloc(fbytes);      // 8 MB normal
  bf16_t* stmp  = (bf16_t*)alloc(fbytes);      // 8 MB normal; attn_b alias after g1b
  bf16_t* shtmp = (bf16_t*)alloc(fbytes);      // 8 MB normal
  bf16_t* kmod  = (bf16_t*)alloc(fbytes);      // 8 MB swizzled
  bf16_t* vtb    = m1b;    // alias: m1b dead after g1a
  bf16_t* attn_b = stmp;   // alias: stmp dead after g1b epilogue

  bf16_t* wtq  = wt + 0 * 512 * 512;
  bf16_t* wtk  = wt + 1 * 512 * 512;
  bf16_t* wtv  = wt + 2 * 512 * 512;
  bf16_t* wts  = wt + 3 * 512 * 512;
  bf16_t* wtsh = wt + 4 * 512 * 512;
  bf16_t* wto  = wt + 5 * 512 * 512;

  DetectArgs da;
  for (int i = 0; i < NIN; ++i) {
    da.p[i] = (const uint16_t*)d_in[i];
    da.n[i] = in_sizes[i] < 2048 ? in_sizes[i] : 2048;
  }
  da.flags = flags;
  hipLaunchKernelGGL(detect_kernel, dim3(NIN), dim3(64), 0, stream, da);

  CvtArgs ca;
  ca.src[0] = d_in[0]; ca.dst[0] = m1b; ca.idx[0] = 0;
  ca.src[1] = d_in[1]; ca.dst[1] = m2b; ca.idx[1] = 1;
  ca.flags = flags;
  hipLaunchKernelGGL(cvt_kernel, dim3(M_ * D_ / 2048, 2), dim3(256), 0, stream, ca);

  TransArgs ta;
  const int widx[6] = {2, 4, 6, 10, 12, 8};
  bf16_t* wdst[6] = {wtq, wtk, wtv, wts, wtsh, wto};
  for (int i = 0; i < 6; ++i) { ta.src[i] = d_in[widx[i]]; ta.srcIdx[i] = widx[i]; ta.dst[i] = wdst[i]; }
  ta.flags = flags;
  hipLaunchKernelGGL(transpose_kernel, dim3(8, 8, 6), dim3(256), 0, stream, ta);

  // g1a: Q, scale, shift projections — 1536 blocks, dbuf staging
  GemmBatch g1;
  g1.A[0] = m1b; g1.A[1] = m2b; g1.A[2] = m2b;
  g1.Bt[0] = wtq; g1.Bt[1] = wts; g1.Bt[2] = wtsh;
  g1.bias[0] = d_in[3];  g1.bIdx[0] = 3;
  g1.bias[1] = d_in[11]; g1.bIdx[1] = 11;
  g1.bias[2] = d_in[13]; g1.bIdx[2] = 13;
  g1.C[0] = q_buf; g1.cIdx[0] = -1;
  g1.C[1] = stmp;  g1.cIdx[1] = -1;
  g1.C[2] = shtmp; g1.cIdx[2] = -1;
  g1.flags = flags;
  hipLaunchKernelGGL(gemm_bt_kernel, dim3(M_ / 128, 8, 3), dim3(256), 0, stream, g1);

  // g1b: K, V projections + fused modulation — 1024 blocks, dbuf staging
  GemmModArgs gm;
  gm.A = m2b;
  gm.Bt[0] = wtk; gm.Bt[1] = wtv;
  gm.bias[0] = d_in[5]; gm.bIdx[0] = 5;
  gm.bias[1] = d_in[7]; gm.bIdx[1] = 7;
  gm.Sc = stmp; gm.Sh = shtmp;
  gm.Kmod = kmod; gm.VtT = vtb;
  gm.flags = flags;
  hipLaunchKernelGGL(gemm_mod_kernel, dim3(M_ / 128, 8, 2), dim3(256), 0, stream, gm);

  // attn: 512 blocks x 256 threads (v6 geometry), dbuf K/V
  hipLaunchKernelGGL(attn_kernel, dim3(512), dim3(256), 0, stream,
                     q_buf, kmod, vtb, attn_b);

  // g2: out = attn @ Wo^T + bo — 512 blocks, dbuf staging
  GemmBatch g2;
  for (int i = 0; i < 3; ++i) {
    g2.A[i] = attn_b;
    g2.Bt[i] = wto;
    g2.bias[i] = d_in[9]; g2.bIdx[i] = 9;
    g2.C[i] = d_out; g2.cIdx[i] = 0;
  }
  g2.flags = flags;
  hipLaunchKernelGGL(gemm_bt_kernel, dim3(M_ / 128, 8, 1), dim3(256), 0, stream, g2);
}